// Round 1
// baseline (431.158 us; speedup 1.0000x reference)
//
#include <hip/hip_runtime.h>
#include <cstdint>
#include <cstddef>

#define TT 1024
#define HH 1024
#define IW 1024
#define EE 16
#define KK 8
#define NSLOT (TT*KK)   // 8192

typedef unsigned short u16;
typedef unsigned int   u32;
typedef __attribute__((ext_vector_type(4))) float f32x4;
typedef __attribute__((ext_vector_type(8))) short s16x8;
typedef __attribute__((ext_vector_type(8))) u16   u16x8;

// fp32 -> bf16 round-to-nearest-even (finite inputs only)
__device__ __forceinline__ u16 f2bf(float f) {
  union { float f; u32 u; } v; v.f = f;
  u32 u = v.u + 0x7fffu + ((v.u >> 16) & 1u);
  return (u16)(u >> 16);
}

__device__ __forceinline__ void gload16(const void* g, void* l) {
  __builtin_amdgcn_global_load_lds(
      (const __attribute__((address_space(1))) u32*)g,
      (__attribute__((address_space(3))) u32*)l, 16, 0, 0);
}

#define MFMA16(a, b, c) __builtin_amdgcn_mfma_f32_16x16x32_bf16((a), (b), (c), 0, 0, 0)

// ---------------- prep kernels ----------------

__global__ void k_cvtx(const float* __restrict__ hs, u16* __restrict__ xb) {
  int g = blockIdx.x * 256 + threadIdx.x;          // 131072 threads, 8 elems each
  const f32x4* s = (const f32x4*)(hs + (size_t)g * 8);
  f32x4 f0 = s[0], f1 = s[1];
  u16x8 p;
#pragma unroll
  for (int i = 0; i < 4; ++i) { p[i] = f2bf(f0[i]); p[i + 4] = f2bf(f1[i]); }
  *(u16x8*)(xb + (size_t)g * 8) = p;
}

__global__ void k_count(const int* __restrict__ idx, int* __restrict__ counts) {
  for (int s = blockIdx.x * 256 + threadIdx.x; s < NSLOT; s += gridDim.x * 256)
    atomicAdd(&counts[idx[s]], 1);
}

__global__ void k_scan(const int* __restrict__ counts, int* __restrict__ offsets,
                       int* __restrict__ cursor) {
  if (threadIdx.x == 0) {
    int r = 0;
    for (int e = 0; e < EE; ++e) { offsets[e] = r; cursor[e] = r; r += counts[e]; }
    offsets[EE] = r;
  }
}

__global__ void k_scatter(const int* __restrict__ idx, int* __restrict__ cursor,
                          int* __restrict__ slot_token, int* __restrict__ inv) {
  for (int s = blockIdx.x * 256 + threadIdx.x; s < NSLOT; s += gridDim.x * 256) {
    int e = idx[s];
    int pos = atomicAdd(&cursor[e], 1);
    slot_token[pos] = s >> 3;   // token id (K=8)
    inv[s] = pos;
  }
}

// ---------------- GEMM1: act = silu(X Wg^T) * (X Wu^T), per expert ----------------
// BM=128 slots, BN=64 channels (gate+up pair), BK=32, 4 waves (2x2), wave tile 64x32.

__global__ __launch_bounds__(256, 2) void k_gemm1(
    const u16* __restrict__ xb,         // [T][H] bf16
    const float* __restrict__ gup,      // [E][2I][H] fp32
    const int* __restrict__ offsets,    // [E+1]
    const int* __restrict__ slot_token, // [NSLOT]
    u16* __restrict__ act)              // [NSLOT][I] bf16
{
  __shared__ __align__(16) u16 As[128 * 32];
  __shared__ __align__(16) u16 Bgs[64 * 32];
  __shared__ __align__(16) u16 Bus[64 * 32];

  const int e = blockIdx.z, mt = blockIdx.y, nt = blockIdx.x;
  const int off = offsets[e];
  const int ne  = offsets[e + 1] - off;
  if (mt * 128 >= ne) return;

  const int tid = threadIdx.x;
  const int lane = tid & 63, wid = tid >> 6;
  const int wm = wid >> 1, wn = wid & 1;

  // A staging (global_load_lds, gathered rows): per wave 2 calls of 16 rows
  const int l4 = lane >> 2;                 // row within 16-row group
  const int lq = lane & 3;                  // physical quarter this lane fills
  const int chunk = lq ^ (l4 & 3);          // source k-chunk (XOR swizzle, write side)
  int tok[2];
#pragma unroll
  for (int q = 0; q < 2; ++q) {
    int grow = mt * 128 + q * 64 + wid * 16 + l4;
    if (grow >= ne) grow = ne - 1;          // clamp: finite garbage, unguarded rows never stored
    tok[q] = slot_token[off + grow];
  }

  // B staging decomposition: 256 threads = 2 tiles x 64 rows x 2 halves (16 fp32 each)
  const int bwhich = tid >> 7;              // 0 = gate, 1 = up
  const int bidx = tid & 127;
  const int br = bidx >> 1, bh = bidx & 1;
  const size_t browg = (size_t)(bwhich ? (IW + nt * 64 + br) : (nt * 64 + br));
  const float* bsrc0 = gup + ((size_t)e * 2 * IW + browg) * HH;
  u16* Bt = bwhich ? Bus : Bgs;
  const int bq0 = (((2 * bh + 0) ^ (br & 3)) << 3);  // u16 offset (swizzled quarter)
  const int bq1 = (((2 * bh + 1) ^ (br & 3)) << 3);

  f32x4 accg[4][2], accu[4][2];
  const f32x4 zz = {0.f, 0.f, 0.f, 0.f};
#pragma unroll
  for (int m = 0; m < 4; ++m)
#pragma unroll
    for (int n = 0; n < 2; ++n) { accg[m][n] = zz; accu[m][n] = zz; }

  const int r16 = lane & 15, kg = lane >> 4;
  const int rq = ((kg ^ (r16 & 3)) << 3);   // swizzled u16 offset of my k-chunk

  for (int kk = 0; kk < HH / 32; ++kk) {
    const int k0 = kk * 32;
    // A: global -> LDS direct (pre-swizzled per-lane source)
#pragma unroll
    for (int q = 0; q < 2; ++q)
      gload16(xb + (size_t)tok[q] * HH + k0 + chunk * 8,
              As + (q * 64 + wid * 16) * 32);
    // B: fp32 -> bf16 reg-staged
    {
      const f32x4* s = (const f32x4*)(bsrc0 + k0 + bh * 16);
      f32x4 f0 = s[0], f1 = s[1], f2 = s[2], f3 = s[3];
      u16x8 p0, p1;
#pragma unroll
      for (int i = 0; i < 4; ++i) {
        p0[i] = f2bf(f0[i]); p0[i + 4] = f2bf(f1[i]);
        p1[i] = f2bf(f2[i]); p1[i + 4] = f2bf(f3[i]);
      }
      *(u16x8*)(Bt + br * 32 + bq0) = p0;
      *(u16x8*)(Bt + br * 32 + bq1) = p1;
    }
    __syncthreads();

    s16x8 a[4], bg[2], bu[2];
#pragma unroll
    for (int m = 0; m < 4; ++m)
      a[m] = *(const s16x8*)(As + (wm * 64 + m * 16 + r16) * 32 + rq);
#pragma unroll
    for (int n = 0; n < 2; ++n) {
      bg[n] = *(const s16x8*)(Bgs + (wn * 32 + n * 16 + r16) * 32 + rq);
      bu[n] = *(const s16x8*)(Bus + (wn * 32 + n * 16 + r16) * 32 + rq);
    }
#pragma unroll
    for (int m = 0; m < 4; ++m)
#pragma unroll
      for (int n = 0; n < 2; ++n) {
        accg[m][n] = MFMA16(a[m], bg[n], accg[m][n]);
        accu[m][n] = MFMA16(a[m], bu[n], accu[m][n]);
      }
    __syncthreads();
  }

  // epilogue: silu(g)*u -> bf16 act
#pragma unroll
  for (int m = 0; m < 4; ++m) {
    const int baserow = mt * 128 + wm * 64 + m * 16 + kg * 4;
#pragma unroll
    for (int n = 0; n < 2; ++n) {
      const int c = nt * 64 + wn * 32 + n * 16 + r16;
#pragma unroll
      for (int j = 0; j < 4; ++j) {
        const int row = baserow + j;
        if (row < ne) {
          float g = accg[m][n][j], u = accu[m][n][j];
          float sv = g / (1.f + __expf(-g));
          act[(size_t)(off + row) * IW + c] = f2bf(sv * u);
        }
      }
    }
  }
}

// ---------------- GEMM2: wdown = act @ down^T, per expert ----------------
// BM=128 slots, BN=128 h, BK=32, 4 waves (2x2), wave tile 64x64.

__global__ __launch_bounds__(256, 2) void k_gemm2(
    const u16* __restrict__ act,        // [NSLOT][I] bf16
    const float* __restrict__ dp,       // [E][H][I] fp32
    const int* __restrict__ offsets,
    float* __restrict__ wdown)          // [NSLOT][H] fp32
{
  __shared__ __align__(16) u16 As[128 * 32];
  __shared__ __align__(16) u16 Bs[128 * 32];

  const int e = blockIdx.z, mt = blockIdx.y, nt = blockIdx.x;
  const int off = offsets[e];
  const int ne  = offsets[e + 1] - off;
  if (mt * 128 >= ne) return;

  const int tid = threadIdx.x;
  const int lane = tid & 63, wid = tid >> 6;
  const int wm = wid >> 1, wn = wid & 1;

  const int l4 = lane >> 2, lq = lane & 3;
  const int chunk = lq ^ (l4 & 3);
  int arow[2];
#pragma unroll
  for (int q = 0; q < 2; ++q) {
    int grow = mt * 128 + q * 64 + wid * 16 + l4;
    if (grow >= ne) grow = ne - 1;
    arow[q] = off + grow;
  }

  const int br = tid >> 1, bh = tid & 1;    // 128 rows x 2 halves
  const float* bsrc0 = dp + ((size_t)e * HH + nt * 128 + br) * IW;
  const int bq0 = (((2 * bh + 0) ^ (br & 3)) << 3);
  const int bq1 = (((2 * bh + 1) ^ (br & 3)) << 3);

  f32x4 acc[4][4];
  const f32x4 zz = {0.f, 0.f, 0.f, 0.f};
#pragma unroll
  for (int m = 0; m < 4; ++m)
#pragma unroll
    for (int n = 0; n < 4; ++n) acc[m][n] = zz;

  const int r16 = lane & 15, kg = lane >> 4;
  const int rq = ((kg ^ (r16 & 3)) << 3);

  for (int kk = 0; kk < IW / 32; ++kk) {
    const int k0 = kk * 32;
#pragma unroll
    for (int q = 0; q < 2; ++q)
      gload16(act + (size_t)arow[q] * IW + k0 + chunk * 8,
              As + (q * 64 + wid * 16) * 32);
    {
      const f32x4* s = (const f32x4*)(bsrc0 + k0 + bh * 16);
      f32x4 f0 = s[0], f1 = s[1], f2 = s[2], f3 = s[3];
      u16x8 p0, p1;
#pragma unroll
      for (int i = 0; i < 4; ++i) {
        p0[i] = f2bf(f0[i]); p0[i + 4] = f2bf(f1[i]);
        p1[i] = f2bf(f2[i]); p1[i + 4] = f2bf(f3[i]);
      }
      *(u16x8*)(Bs + br * 32 + bq0) = p0;
      *(u16x8*)(Bs + br * 32 + bq1) = p1;
    }
    __syncthreads();

    s16x8 a[4], b[4];
#pragma unroll
    for (int m = 0; m < 4; ++m)
      a[m] = *(const s16x8*)(As + (wm * 64 + m * 16 + r16) * 32 + rq);
#pragma unroll
    for (int n = 0; n < 4; ++n)
      b[n] = *(const s16x8*)(Bs + (wn * 64 + n * 16 + r16) * 32 + rq);
#pragma unroll
    for (int m = 0; m < 4; ++m)
#pragma unroll
      for (int n = 0; n < 4; ++n)
        acc[m][n] = MFMA16(a[m], b[n], acc[m][n]);
    __syncthreads();
  }

#pragma unroll
  for (int m = 0; m < 4; ++m) {
    const int baserow = mt * 128 + wm * 64 + m * 16 + kg * 4;
#pragma unroll
    for (int n = 0; n < 4; ++n) {
      const int h = nt * 128 + wn * 64 + n * 16 + r16;
#pragma unroll
      for (int j = 0; j < 4; ++j) {
        const int row = baserow + j;
        if (row < ne)
          wdown[(size_t)(off + row) * HH + h] = acc[m][n][j];
      }
    }
  }
}

// ---------------- combine: out[t,h] = sum_k w[t,k] * wdown[inv[t,k]][h] ----------------

__global__ void k_combine(const float* __restrict__ wdown, const int* __restrict__ inv,
                          const float* __restrict__ tkw, float* __restrict__ out) {
  int g = blockIdx.x * 256 + threadIdx.x;   // T*H/4 threads
  int t = g >> 8;                           // H/4 = 256 per token
  int hv = (g & 255) * 4;
  f32x4 a = {0.f, 0.f, 0.f, 0.f};
#pragma unroll
  for (int k = 0; k < KK; ++k) {
    int pos = inv[t * KK + k];
    float w = tkw[t * KK + k];
    f32x4 v = *(const f32x4*)(wdown + (size_t)pos * HH + hv);
    a += w * v;
  }
  *(f32x4*)(out + (size_t)t * HH + hv) = a;
}

// ---------------- host ----------------

extern "C" void kernel_launch(void* const* d_in, const int* in_sizes, int n_in,
                              void* d_out, int out_size, void* d_ws, size_t ws_size,
                              hipStream_t stream) {
  const float* hs  = (const float*)d_in[0];
  const int*   idx = (const int*)d_in[1];
  const float* tkw = (const float*)d_in[2];
  const float* gup = (const float*)d_in[3];
  const float* dpw = (const float*)d_in[4];
  float* out = (float*)d_out;

  char* ws = (char*)d_ws;
  size_t o = 0;
  u16* xb = (u16*)(ws + o);         o += (size_t)TT * HH * 2;       // 2 MiB
  int* counts  = (int*)(ws + o);    o += 64;
  int* cursor  = (int*)(ws + o);    o += 64;
  int* offsets = (int*)(ws + o);    o += 128;
  int* slot_token = (int*)(ws + o); o += (size_t)NSLOT * 4;
  int* inv     = (int*)(ws + o);    o += (size_t)NSLOT * 4;
  o = (o + 255) & ~(size_t)255;
  u16* act = (u16*)(ws + o);        o += (size_t)NSLOT * IW * 2;    // 16 MiB
  float* wdown = (float*)(ws + o);  o += (size_t)NSLOT * HH * 4;    // 32 MiB
  // total ~50.4 MiB of ws

  hipMemsetAsync(counts, 0, 64, stream);
  k_cvtx<<<TT * HH / (256 * 8), 256, 0, stream>>>(hs, xb);
  k_count<<<16, 256, 0, stream>>>(idx, counts);
  k_scan<<<1, 64, 0, stream>>>(counts, offsets, cursor);
  k_scatter<<<16, 256, 0, stream>>>(idx, cursor, slot_token, inv);
  k_gemm1<<<dim3(IW / 64, NSLOT / 128, EE), 256, 0, stream>>>(xb, gup, offsets, slot_token, act);
  k_gemm2<<<dim3(HH / 128, NSLOT / 128, EE), 256, 0, stream>>>(act, dpw, offsets, wdown);
  k_combine<<<TT * HH / 4 / 256, 256, 0, stream>>>(wdown, inv, tkw, out);
}

// Round 2
// 410.549 us; speedup vs baseline: 1.0502x; 1.0502x over previous
//
#include <hip/hip_runtime.h>
#include <cstdint>
#include <cstddef>

#define TT 1024
#define HH 1024
#define IW 1024
#define EE 16
#define KK 8
#define NSLOT (TT*KK)   // 8192
#define NTMAX 80        // max active (expert, mtile) pairs: 8192/128 + 16

typedef unsigned short u16;
typedef unsigned int   u32;
typedef __attribute__((ext_vector_type(4))) float f32x4;
typedef __attribute__((ext_vector_type(8))) short s16x8;
typedef __attribute__((ext_vector_type(8))) u16   u16x8;

// fp32 -> bf16 round-to-nearest-even (finite inputs only)
__device__ __forceinline__ u16 f2bf(float f) {
  union { float f; u32 u; } v; v.f = f;
  u32 u = v.u + 0x7fffu + ((v.u >> 16) & 1u);
  return (u16)(u >> 16);
}

__device__ __forceinline__ void gload16(const void* g, void* l) {
  __builtin_amdgcn_global_load_lds(
      (const __attribute__((address_space(1))) u32*)g,
      (__attribute__((address_space(3))) u32*)l, 16, 0, 0);
}

#define MFMA16(a, b, c) __builtin_amdgcn_mfma_f32_16x16x32_bf16((a), (b), (c), 0, 0, 0)

// ---------------- prep kernels ----------------

// fp32 -> bf16, 8 elems/thread, exact-size launch
__global__ void k_cvt(const float* __restrict__ src, u16* __restrict__ dst) {
  int g = blockIdx.x * 256 + threadIdx.x;
  const f32x4* s = (const f32x4*)(src + (size_t)g * 8);
  f32x4 f0 = s[0], f1 = s[1];
  u16x8 p;
#pragma unroll
  for (int i = 0; i < 4; ++i) { p[i] = f2bf(f0[i]); p[i + 4] = f2bf(f1[i]); }
  *(u16x8*)(dst + (size_t)g * 8) = p;
}

__global__ void k_count(const int* __restrict__ idx, int* __restrict__ counts) {
  for (int s = blockIdx.x * 256 + threadIdx.x; s < NSLOT; s += gridDim.x * 256)
    atomicAdd(&counts[idx[s]], 1);
}

__global__ void k_scan(const int* __restrict__ counts, int* __restrict__ offsets,
                       int* __restrict__ cursor, int* __restrict__ tile_e,
                       int* __restrict__ tile_mt) {
  if (threadIdx.x == 0) {
    int r = 0, t = 0;
    for (int e = 0; e < EE; ++e) {
      offsets[e] = r; cursor[e] = r;
      int c = counts[e];
      for (int mt = 0; mt * 128 < c; ++mt) { tile_e[t] = e; tile_mt[t] = mt; ++t; }
      r += c;
    }
    offsets[EE] = r;
    for (; t < NTMAX; ++t) tile_e[t] = -1;
  }
}

__global__ void k_scatter(const int* __restrict__ idx, const float* __restrict__ tkw,
                          int* __restrict__ cursor, int* __restrict__ slot_token,
                          float* __restrict__ slot_w, int* __restrict__ inv) {
  for (int s = blockIdx.x * 256 + threadIdx.x; s < NSLOT; s += gridDim.x * 256) {
    int e = idx[s];
    int pos = atomicAdd(&cursor[e], 1);
    slot_token[pos] = s >> 3;   // token id (K=8)
    slot_w[pos] = tkw[s];
    inv[s] = pos;
  }
}

// ---------------- GEMM1: act = w * silu(X Wg^T) * (X Wu^T), per expert ----------------
// BM=128 slots, BN=64 channels (64 gate rows + 64 up rows), BK=32, 4 waves (2x2),
// wave tile 64x32(x2). All staging via global_load_lds (bf16), pre-swizzled source.
// Swizzle: physical quarter p of row r holds source k-chunk p ^ ((r>>1)&3)  -> 2-way reads.

__global__ __launch_bounds__(256, 2) void k_gemm1(
    const u16* __restrict__ xb,         // [T][H] bf16
    const u16* __restrict__ gupb,       // [E][2I][H] bf16
    const int* __restrict__ offsets,    // [E+1]
    const int* __restrict__ slot_token, // [NSLOT]
    const float* __restrict__ slot_w,   // [NSLOT]
    const int* __restrict__ tile_e,
    const int* __restrict__ tile_mt,
    u16* __restrict__ act)              // [NSLOT][I] bf16
{
  __shared__ __align__(16) u16 As[128 * 32];
  __shared__ __align__(16) u16 Bgs[64 * 32];
  __shared__ __align__(16) u16 Bus[64 * 32];

  const int e = tile_e[blockIdx.y];
  if (e < 0) return;
  const int mt = tile_mt[blockIdx.y], nt = blockIdx.x;
  const int off = offsets[e];
  const int ne  = offsets[e + 1] - off;

  const int tid = threadIdx.x;
  const int lane = tid & 63, wid = tid >> 6;
  const int wm = wid >> 1, wn = wid & 1;

  // staging lane decomposition: 16 rows per gload16 call
  const int l4 = lane >> 2;                   // row within 16-row group
  const int lq = lane & 3;                    // physical quarter this lane fills
  const int chunk = lq ^ ((l4 >> 1) & 3);     // source k-chunk (write-side swizzle)

  // A source rows (gathered)
  const u16* asrc[2];
#pragma unroll
  for (int q = 0; q < 2; ++q) {
    int grow = mt * 128 + q * 64 + wid * 16 + l4;
    if (grow >= ne) grow = ne - 1;            // clamp: garbage rows never stored
    asrc[q] = xb + (size_t)slot_token[off + grow] * HH + chunk * 8;
  }
  // B source rows (gate / up), wave wid stages rows wid*16..wid*16+15 of each
  const int bch = nt * 64 + wid * 16 + l4;    // output channel
  const u16* bgsrc = gupb + ((size_t)e * 2 * IW + bch) * HH + chunk * 8;
  const u16* busrc = bgsrc + (size_t)IW * HH;
  u16* const adst0 = As + (0 * 64 + wid * 16) * 32;
  u16* const adst1 = As + (1 * 64 + wid * 16) * 32;
  u16* const bgdst = Bgs + (wid * 16) * 32;
  u16* const budst = Bus + (wid * 16) * 32;

  f32x4 accg[4][2], accu[4][2];
  const f32x4 zz = {0.f, 0.f, 0.f, 0.f};
#pragma unroll
  for (int m = 0; m < 4; ++m)
#pragma unroll
    for (int n = 0; n < 2; ++n) { accg[m][n] = zz; accu[m][n] = zz; }

  const int r16 = lane & 15, kg = lane >> 4;
  const int rq = ((kg ^ ((r16 >> 1) & 3)) << 3);  // swizzled u16 offset of my k-chunk

  for (int kk = 0; kk < HH / 32; ++kk) {
    const int k0 = kk * 32;
    gload16(asrc[0] + k0, adst0);
    gload16(asrc[1] + k0, adst1);
    gload16(bgsrc + k0, bgdst);
    gload16(busrc + k0, budst);
    __syncthreads();

    s16x8 a[4], bg[2], bu[2];
#pragma unroll
    for (int m = 0; m < 4; ++m)
      a[m] = *(const s16x8*)(As + (wm * 64 + m * 16 + r16) * 32 + rq);
#pragma unroll
    for (int n = 0; n < 2; ++n) {
      bg[n] = *(const s16x8*)(Bgs + (wn * 32 + n * 16 + r16) * 32 + rq);
      bu[n] = *(const s16x8*)(Bus + (wn * 32 + n * 16 + r16) * 32 + rq);
    }
#pragma unroll
    for (int m = 0; m < 4; ++m)
#pragma unroll
      for (int n = 0; n < 2; ++n) {
        accg[m][n] = MFMA16(a[m], bg[n], accg[m][n]);
        accu[m][n] = MFMA16(a[m], bu[n], accu[m][n]);
      }
    __syncthreads();
  }

  // epilogue: w * silu(g) * u -> bf16 act
#pragma unroll
  for (int m = 0; m < 4; ++m) {
    const int baserow = mt * 128 + wm * 64 + m * 16 + kg * 4;
#pragma unroll
    for (int n = 0; n < 2; ++n) {
      const int c = nt * 64 + wn * 32 + n * 16 + r16;
#pragma unroll
      for (int j = 0; j < 4; ++j) {
        const int row = baserow + j;
        if (row < ne) {
          float g = accg[m][n][j], u = accu[m][n][j];
          float sv = g / (1.f + __expf(-g));
          act[(size_t)(off + row) * IW + c] = f2bf(sv * u * slot_w[off + row]);
        }
      }
    }
  }
}

// ---------------- GEMM2: wdown = act @ down^T, per expert ----------------
// BM=128 slots, BN=128 h, BK=32, 4 waves (2x2), wave tile 64x64. m97 structure.

__global__ __launch_bounds__(256, 2) void k_gemm2(
    const u16* __restrict__ act,        // [NSLOT][I] bf16
    const u16* __restrict__ dpb,        // [E][H][I] bf16
    const int* __restrict__ offsets,
    const int* __restrict__ tile_e,
    const int* __restrict__ tile_mt,
    float* __restrict__ wdown)          // [NSLOT][H] fp32
{
  __shared__ __align__(16) u16 As[128 * 32];
  __shared__ __align__(16) u16 Bs[128 * 32];

  const int e = tile_e[blockIdx.y];
  if (e < 0) return;
  const int mt = tile_mt[blockIdx.y], nt = blockIdx.x;
  const int off = offsets[e];
  const int ne  = offsets[e + 1] - off;

  const int tid = threadIdx.x;
  const int lane = tid & 63, wid = tid >> 6;
  const int wm = wid >> 1, wn = wid & 1;

  const int l4 = lane >> 2, lq = lane & 3;
  const int chunk = lq ^ ((l4 >> 1) & 3);

  // A rows are contiguous slots (act is expert-sorted)
  const u16* asrc[2];
#pragma unroll
  for (int q = 0; q < 2; ++q) {
    int grow = mt * 128 + q * 64 + wid * 16 + l4;
    if (grow >= ne) grow = ne - 1;
    asrc[q] = act + (size_t)(off + grow) * IW + chunk * 8;
  }
  // B rows: down[e][nt*128 + r][*]
  const u16* bsrc[2];
#pragma unroll
  for (int q = 0; q < 2; ++q)
    bsrc[q] = dpb + ((size_t)e * HH + nt * 128 + q * 64 + wid * 16 + l4) * IW + chunk * 8;

  u16* const adst0 = As + (0 * 64 + wid * 16) * 32;
  u16* const adst1 = As + (1 * 64 + wid * 16) * 32;
  u16* const bdst0 = Bs + (0 * 64 + wid * 16) * 32;
  u16* const bdst1 = Bs + (1 * 64 + wid * 16) * 32;

  f32x4 acc[4][4];
  const f32x4 zz = {0.f, 0.f, 0.f, 0.f};
#pragma unroll
  for (int m = 0; m < 4; ++m)
#pragma unroll
    for (int n = 0; n < 4; ++n) acc[m][n] = zz;

  const int r16 = lane & 15, kg = lane >> 4;
  const int rq = ((kg ^ ((r16 >> 1) & 3)) << 3);

  for (int kk = 0; kk < IW / 32; ++kk) {
    const int k0 = kk * 32;
    gload16(asrc[0] + k0, adst0);
    gload16(asrc[1] + k0, adst1);
    gload16(bsrc[0] + k0, bdst0);
    gload16(bsrc[1] + k0, bdst1);
    __syncthreads();

    s16x8 a[4], b[4];
#pragma unroll
    for (int m = 0; m < 4; ++m)
      a[m] = *(const s16x8*)(As + (wm * 64 + m * 16 + r16) * 32 + rq);
#pragma unroll
    for (int n = 0; n < 4; ++n)
      b[n] = *(const s16x8*)(Bs + (wn * 64 + n * 16 + r16) * 32 + rq);
#pragma unroll
    for (int m = 0; m < 4; ++m)
#pragma unroll
      for (int n = 0; n < 4; ++n)
        acc[m][n] = MFMA16(a[m], b[n], acc[m][n]);
    __syncthreads();
  }

#pragma unroll
  for (int m = 0; m < 4; ++m) {
    const int baserow = mt * 128 + wm * 64 + m * 16 + kg * 4;
#pragma unroll
    for (int n = 0; n < 4; ++n) {
      const int h = nt * 128 + wn * 64 + n * 16 + r16;
#pragma unroll
      for (int j = 0; j < 4; ++j) {
        const int row = baserow + j;
        if (row < ne)
          wdown[(size_t)(off + row) * HH + h] = acc[m][n][j];
      }
    }
  }
}

// ---------------- combine: out[t,h] = sum_k wdown[inv[t,k]][h]  (w folded into act) ----

__global__ void k_combine(const float* __restrict__ wdown, const int* __restrict__ inv,
                          float* __restrict__ out) {
  int g = blockIdx.x * 256 + threadIdx.x;   // T*H/4 threads
  int t = g >> 8;                           // H/4 = 256 per token
  int hv = (g & 255) * 4;
  f32x4 a = {0.f, 0.f, 0.f, 0.f};
#pragma unroll
  for (int k = 0; k < KK; ++k) {
    int pos = inv[t * KK + k];
    f32x4 v = *(const f32x4*)(wdown + (size_t)pos * HH + hv);
    a += v;
  }
  *(f32x4*)(out + (size_t)t * HH + hv) = a;
}

// ---------------- host ----------------

extern "C" void kernel_launch(void* const* d_in, const int* in_sizes, int n_in,
                              void* d_out, int out_size, void* d_ws, size_t ws_size,
                              hipStream_t stream) {
  const float* hs  = (const float*)d_in[0];
  const int*   idx = (const int*)d_in[1];
  const float* tkw = (const float*)d_in[2];
  const float* gup = (const float*)d_in[3];
  const float* dpw = (const float*)d_in[4];
  float* out = (float*)d_out;

  char* ws = (char*)d_ws;
  size_t o = 0;
  u16* xb   = (u16*)(ws + o);       o += (size_t)TT * HH * 2;            // 2 MiB
  u16* gupb = (u16*)(ws + o);       o += (size_t)EE * 2 * IW * HH * 2;   // 64 MiB
  u16* dpb  = (u16*)(ws + o);       o += (size_t)EE * HH * IW * 2;       // 32 MiB
  int* counts  = (int*)(ws + o);    o += 64;
  int* cursor  = (int*)(ws + o);    o += 64;
  int* offsets = (int*)(ws + o);    o += 128;
  int* tile_e  = (int*)(ws + o);    o += NTMAX * 4;
  int* tile_mt = (int*)(ws + o);    o += NTMAX * 4;
  int* slot_token = (int*)(ws + o); o += (size_t)NSLOT * 4;
  int* inv     = (int*)(ws + o);    o += (size_t)NSLOT * 4;
  float* slot_w = (float*)(ws + o); o += (size_t)NSLOT * 4;
  o = (o + 255) & ~(size_t)255;
  u16* act = (u16*)(ws + o);        o += (size_t)NSLOT * IW * 2;         // 16 MiB
  float* wdown = (float*)(ws + o);  o += (size_t)NSLOT * HH * 4;         // 32 MiB
  // total ~146.5 MiB of ws

  hipMemsetAsync(counts, 0, 64, stream);
  k_cvt<<<TT * HH / (256 * 8), 256, 0, stream>>>(hs, xb);
  k_cvt<<<(int)((size_t)EE * 2 * IW * HH / (256 * 8)), 256, 0, stream>>>(gup, gupb);
  k_cvt<<<(int)((size_t)EE * HH * IW / (256 * 8)), 256, 0, stream>>>(dpw, dpb);
  k_count<<<16, 256, 0, stream>>>(idx, counts);
  k_scan<<<1, 64, 0, stream>>>(counts, offsets, cursor, tile_e, tile_mt);
  k_scatter<<<16, 256, 0, stream>>>(idx, tkw, cursor, slot_token, slot_w, inv);
  k_gemm1<<<dim3(IW / 64, NTMAX), 256, 0, stream>>>(xb, gupb, offsets, slot_token,
                                                    slot_w, tile_e, tile_mt, act);
  k_gemm2<<<dim3(HH / 128, NTMAX), 256, 0, stream>>>(act, dpb, offsets, tile_e, tile_mt, wdown);
  k_combine<<<TT * HH / 4 / 256, 256, 0, stream>>>(wdown, inv, out);
}

// Round 4
// 387.263 us; speedup vs baseline: 1.1133x; 1.0601x over previous
//
#include <hip/hip_runtime.h>
#include <cstdint>
#include <cstddef>

#define TT 1024
#define HH 1024
#define IW 1024
#define EE 16
#define KK 8
#define NSLOT (TT*KK)   // 8192
#define NTMAX 80        // max active (expert, mtile) pairs: 8192/128 + 16

typedef unsigned short u16;
typedef unsigned int   u32;
typedef __attribute__((ext_vector_type(4))) float f32x4;
typedef __attribute__((ext_vector_type(8))) short s16x8;
typedef __attribute__((ext_vector_type(8))) u16   u16x8;

// fp32 -> bf16 round-to-nearest-even (finite inputs only)
__device__ __forceinline__ u16 f2bf(float f) {
  union { float f; u32 u; } v; v.f = f;
  u32 u = v.u + 0x7fffu + ((v.u >> 16) & 1u);
  return (u16)(u >> 16);
}
__device__ __forceinline__ float bf2f(u16 b) {
  union { u32 u; float f; } v; v.u = (u32)b << 16;
  return v.f;
}

__device__ __forceinline__ void gload16(const void* g, void* l) {
  __builtin_amdgcn_global_load_lds(
      (const __attribute__((address_space(1))) u32*)g,
      (__attribute__((address_space(3))) u32*)l, 16, 0, 0);
}

#define MFMA16(a, b, c) __builtin_amdgcn_mfma_f32_16x16x32_bf16((a), (b), (c), 0, 0, 0)

// ---------------- fused conversion: x, gate_up, down -> bf16 ----------------
// 2048 elems per block (256 thr x 8). Segments: [0,512)=x, [512,16896)=gup, rest=dp.

__global__ void k_cvt_all(const float* __restrict__ hs, const float* __restrict__ gup,
                          const float* __restrict__ dp, u16* __restrict__ xb,
                          u16* __restrict__ gupb, u16* __restrict__ dpb) {
  int b = blockIdx.x;
  const float* src; u16* dst; size_t rel;
  if (b < 512)        { src = hs;  dst = xb;   rel = (size_t)b; }
  else if (b < 16896) { src = gup; dst = gupb; rel = (size_t)(b - 512); }
  else                { src = dp;  dst = dpb;  rel = (size_t)(b - 16896); }
  size_t g = rel * 2048 + (size_t)threadIdx.x * 8;
  const f32x4* s = (const f32x4*)(src + g);
  f32x4 f0 = s[0], f1 = s[1];
  u16x8 p;
#pragma unroll
  for (int i = 0; i < 4; ++i) { p[i] = f2bf(f0[i]); p[i + 4] = f2bf(f1[i]); }
  *(u16x8*)(dst + g) = p;
}

// ---------------- fused routing: count + scan + scatter + tile list, ONE block ----

__global__ void k_route(const int* __restrict__ idx, const float* __restrict__ tkw,
                        int* __restrict__ offsets, int* __restrict__ slot_token,
                        float* __restrict__ slot_w, int* __restrict__ inv,
                        int* __restrict__ tile_e, int* __restrict__ tile_mt) {
  __shared__ int cnt[EE], cur[EE];
  const int tid = threadIdx.x;
  if (tid < EE) cnt[tid] = 0;
  __syncthreads();
  for (int s = tid; s < NSLOT; s += 256) atomicAdd(&cnt[idx[s]], 1);
  __syncthreads();
  if (tid == 0) {
    int r = 0, t = 0;
    for (int e = 0; e < EE; ++e) {
      offsets[e] = r; cur[e] = r;
      int c = cnt[e];
      for (int mt = 0; mt * 128 < c; ++mt) { tile_e[t] = e; tile_mt[t] = mt; ++t; }
      r += c;
    }
    offsets[EE] = r;
    for (; t < NTMAX; ++t) tile_e[t] = -1;
  }
  __syncthreads();
  for (int s = tid; s < NSLOT; s += 256) {
    int e = idx[s];
    int pos = atomicAdd(&cur[e], 1);
    slot_token[pos] = s >> 3;   // token id (K=8)
    slot_w[pos] = tkw[s];
    inv[s] = pos;
  }
}

// ---------------- GEMM1: act = w * silu(X Wg^T) * (X Wu^T), per expert ----------------
// BM=128 slots, BN=64 channels (gate+up), BK=32, 4 waves (2x2), 2-phase dbuf pipeline.
// Swizzle: physical quarter p of row r holds source k-chunk p ^ ((r>>1)&3).

#define G1_ASZ (128*32)
#define G1_BSZ (64*32)

__global__ __launch_bounds__(256, 2) void k_gemm1(
    const u16* __restrict__ xb,         // [T][H] bf16
    const u16* __restrict__ gupb,       // [E][2I][H] bf16
    const int* __restrict__ offsets,    // [E+1]
    const int* __restrict__ slot_token, // [NSLOT]
    const float* __restrict__ slot_w,   // [NSLOT]
    const int* __restrict__ tile_e,
    const int* __restrict__ tile_mt,
    u16* __restrict__ act)              // [NSLOT][I] bf16
{
  __shared__ __align__(16) u16 As[2 * G1_ASZ];
  __shared__ __align__(16) u16 Bgs[2 * G1_BSZ];
  __shared__ __align__(16) u16 Bus[2 * G1_BSZ];

  const int e = tile_e[blockIdx.y];
  if (e < 0) return;
  const int mt = tile_mt[blockIdx.y], nt = blockIdx.x;
  const int off = offsets[e];
  const int ne  = offsets[e + 1] - off;

  const int tid = threadIdx.x;
  const int lane = tid & 63, wid = tid >> 6;
  const int wm = wid >> 1, wn = wid & 1;

  // staging lane decomposition: 16 rows per gload16 call
  const int l4 = lane >> 2;                   // row within 16-row group
  const int lq = lane & 3;                    // physical quarter this lane fills
  const int chunk = lq ^ ((l4 >> 1) & 3);     // source k-chunk (write-side swizzle)

  const u16* asrc[2];
#pragma unroll
  for (int q = 0; q < 2; ++q) {
    int grow = mt * 128 + q * 64 + wid * 16 + l4;
    if (grow >= ne) grow = ne - 1;            // clamp: garbage rows never stored
    asrc[q] = xb + (size_t)slot_token[off + grow] * HH + chunk * 8;
  }
  const int bch = nt * 64 + wid * 16 + l4;    // output channel
  const u16* bgsrc = gupb + ((size_t)e * 2 * IW + bch) * HH + chunk * 8;
  const u16* busrc = bgsrc + (size_t)IW * HH;
  const int ad0 = (0 * 64 + wid * 16) * 32;
  const int ad1 = (1 * 64 + wid * 16) * 32;
  const int bd  = (wid * 16) * 32;

  f32x4 accg[4][2], accu[4][2];
  const f32x4 zz = {0.f, 0.f, 0.f, 0.f};
#pragma unroll
  for (int m = 0; m < 4; ++m)
#pragma unroll
    for (int n = 0; n < 2; ++n) { accg[m][n] = zz; accu[m][n] = zz; }

  const int r16 = lane & 15, kg = lane >> 4;
  const int rq = ((kg ^ ((r16 >> 1) & 3)) << 3);  // swizzled u16 offset of my k-chunk

  // prologue: stage tile 0 into buffer 0
  gload16(asrc[0], As + ad0);
  gload16(asrc[1], As + ad1);
  gload16(bgsrc,   Bgs + bd);
  gload16(busrc,   Bus + bd);
  __syncthreads();

  for (int kk = 0; kk < HH / 32; ++kk) {
    const int cur = kk & 1;
    if (kk + 1 < HH / 32) {                   // issue next-tile loads FIRST (overlap)
      const int nb = cur ^ 1, k0 = (kk + 1) * 32;
      gload16(asrc[0] + k0, As + nb * G1_ASZ + ad0);
      gload16(asrc[1] + k0, As + nb * G1_ASZ + ad1);
      gload16(bgsrc   + k0, Bgs + nb * G1_BSZ + bd);
      gload16(busrc   + k0, Bus + nb * G1_BSZ + bd);
    }
    const u16* Ab  = As  + cur * G1_ASZ;
    const u16* Bgb = Bgs + cur * G1_BSZ;
    const u16* Bub = Bus + cur * G1_BSZ;

    s16x8 a[4], bg[2], bu[2];
#pragma unroll
    for (int m = 0; m < 4; ++m)
      a[m] = *(const s16x8*)(Ab + (wm * 64 + m * 16 + r16) * 32 + rq);
#pragma unroll
    for (int n = 0; n < 2; ++n) {
      bg[n] = *(const s16x8*)(Bgb + (wn * 32 + n * 16 + r16) * 32 + rq);
      bu[n] = *(const s16x8*)(Bub + (wn * 32 + n * 16 + r16) * 32 + rq);
    }
#pragma unroll
    for (int m = 0; m < 4; ++m)
#pragma unroll
      for (int n = 0; n < 2; ++n) {
        accg[m][n] = MFMA16(a[m], bg[n], accg[m][n]);
        accu[m][n] = MFMA16(a[m], bu[n], accu[m][n]);
      }
    __syncthreads();   // drains vmcnt (next buffer ready) + guards cur reuse
  }

  // epilogue: w * silu(g) * u -> bf16 act
#pragma unroll
  for (int m = 0; m < 4; ++m) {
    const int baserow = mt * 128 + wm * 64 + m * 16 + kg * 4;
#pragma unroll
    for (int n = 0; n < 2; ++n) {
      const int c = nt * 64 + wn * 32 + n * 16 + r16;
#pragma unroll
      for (int j = 0; j < 4; ++j) {
        const int row = baserow + j;
        if (row < ne) {
          float g = accg[m][n][j], u = accu[m][n][j];
          float sv = g / (1.f + __expf(-g));
          act[(size_t)(off + row) * IW + c] = f2bf(sv * u * slot_w[off + row]);
        }
      }
    }
  }
}

// ---------------- GEMM2: wdown = act @ down^T (bf16 out), per expert ----------------
// BM=128 slots, BN=128 h, BK=32, 4 waves (2x2), 2-phase dbuf pipeline.

#define G2_SZ (128*32)

__global__ __launch_bounds__(256, 2) void k_gemm2(
    const u16* __restrict__ act,        // [NSLOT][I] bf16
    const u16* __restrict__ dpb,        // [E][H][I] bf16
    const int* __restrict__ offsets,
    const int* __restrict__ tile_e,
    const int* __restrict__ tile_mt,
    u16* __restrict__ wdown)            // [NSLOT][H] bf16
{
  __shared__ __align__(16) u16 As[2 * G2_SZ];
  __shared__ __align__(16) u16 Bs[2 * G2_SZ];

  const int e = tile_e[blockIdx.y];
  if (e < 0) return;
  const int mt = tile_mt[blockIdx.y], nt = blockIdx.x;
  const int off = offsets[e];
  const int ne  = offsets[e + 1] - off;

  const int tid = threadIdx.x;
  const int lane = tid & 63, wid = tid >> 6;
  const int wm = wid >> 1, wn = wid & 1;

  const int l4 = lane >> 2, lq = lane & 3;
  const int chunk = lq ^ ((l4 >> 1) & 3);

  const u16* asrc[2];
#pragma unroll
  for (int q = 0; q < 2; ++q) {
    int grow = mt * 128 + q * 64 + wid * 16 + l4;
    if (grow >= ne) grow = ne - 1;
    asrc[q] = act + (size_t)(off + grow) * IW + chunk * 8;
  }
  const u16* bsrc[2];
#pragma unroll
  for (int q = 0; q < 2; ++q)
    bsrc[q] = dpb + ((size_t)e * HH + nt * 128 + q * 64 + wid * 16 + l4) * IW + chunk * 8;

  const int d0 = (0 * 64 + wid * 16) * 32;
  const int d1 = (1 * 64 + wid * 16) * 32;

  f32x4 acc[4][4];
  const f32x4 zz = {0.f, 0.f, 0.f, 0.f};
#pragma unroll
  for (int m = 0; m < 4; ++m)
#pragma unroll
    for (int n = 0; n < 4; ++n) acc[m][n] = zz;

  const int r16 = lane & 15, kg = lane >> 4;
  const int rq = ((kg ^ ((r16 >> 1) & 3)) << 3);

  gload16(asrc[0], As + d0);
  gload16(asrc[1], As + d1);
  gload16(bsrc[0], Bs + d0);
  gload16(bsrc[1], Bs + d1);
  __syncthreads();

  for (int kk = 0; kk < IW / 32; ++kk) {
    const int cur = kk & 1;
    if (kk + 1 < IW / 32) {
      const int nb = cur ^ 1, k0 = (kk + 1) * 32;
      gload16(asrc[0] + k0, As + nb * G2_SZ + d0);
      gload16(asrc[1] + k0, As + nb * G2_SZ + d1);
      gload16(bsrc[0] + k0, Bs + nb * G2_SZ + d0);
      gload16(bsrc[1] + k0, Bs + nb * G2_SZ + d1);
    }
    const u16* Ab = As + cur * G2_SZ;
    const u16* Bb = Bs + cur * G2_SZ;

    s16x8 a[4], b[4];
#pragma unroll
    for (int m = 0; m < 4; ++m)
      a[m] = *(const s16x8*)(Ab + (wm * 64 + m * 16 + r16) * 32 + rq);
#pragma unroll
    for (int n = 0; n < 4; ++n)
      b[n] = *(const s16x8*)(Bb + (wn * 64 + n * 16 + r16) * 32 + rq);
#pragma unroll
    for (int m = 0; m < 4; ++m)
#pragma unroll
      for (int n = 0; n < 4; ++n)
        acc[m][n] = MFMA16(a[m], b[n], acc[m][n]);
    __syncthreads();
  }

#pragma unroll
  for (int m = 0; m < 4; ++m) {
    const int baserow = mt * 128 + wm * 64 + m * 16 + kg * 4;
#pragma unroll
    for (int n = 0; n < 4; ++n) {
      const int h = nt * 128 + wn * 64 + n * 16 + r16;
#pragma unroll
      for (int j = 0; j < 4; ++j) {
        const int row = baserow + j;
        if (row < ne)
          wdown[(size_t)(off + row) * HH + h] = f2bf(acc[m][n][j]);
      }
    }
  }
}

// ---------------- combine: out[t,h] = sum_k wdown[inv[t,k]][h]  (w folded into act) ----

__global__ void k_combine(const u16* __restrict__ wdown, const int* __restrict__ inv,
                          float* __restrict__ out) {
  int g = blockIdx.x * 256 + threadIdx.x;   // T*H/8 threads
  int t = g >> 7;                           // 128 threads per token
  int hv = (g & 127) * 8;
  const int* ip = inv + t * KK;
  float acc[8] = {0.f, 0.f, 0.f, 0.f, 0.f, 0.f, 0.f, 0.f};
#pragma unroll
  for (int k = 0; k < KK; ++k) {
    int pos = ip[k];
    u16x8 v = *(const u16x8*)(wdown + (size_t)pos * HH + hv);
#pragma unroll
    for (int j = 0; j < 8; ++j) acc[j] += bf2f(v[j]);
  }
  f32x4 o0 = {acc[0], acc[1], acc[2], acc[3]};
  f32x4 o1 = {acc[4], acc[5], acc[6], acc[7]};
  *(f32x4*)(out + (size_t)t * HH + hv)     = o0;
  *(f32x4*)(out + (size_t)t * HH + hv + 4) = o1;
}

// ---------------- host ----------------

extern "C" void kernel_launch(void* const* d_in, const int* in_sizes, int n_in,
                              void* d_out, int out_size, void* d_ws, size_t ws_size,
                              hipStream_t stream) {
  const float* hs  = (const float*)d_in[0];
  const int*   idx = (const int*)d_in[1];
  const float* tkw = (const float*)d_in[2];
  const float* gup = (const float*)d_in[3];
  const float* dpw = (const float*)d_in[4];
  float* out = (float*)d_out;

  char* ws = (char*)d_ws;
  size_t o = 0;
  u16* xb   = (u16*)(ws + o);       o += (size_t)TT * HH * 2;            // 2 MiB
  u16* gupb = (u16*)(ws + o);       o += (size_t)EE * 2 * IW * HH * 2;   // 64 MiB
  u16* dpb  = (u16*)(ws + o);       o += (size_t)EE * HH * IW * 2;       // 32 MiB
  int* offsets = (int*)(ws + o);    o += 128;
  int* tile_e  = (int*)(ws + o);    o += NTMAX * 4;
  int* tile_mt = (int*)(ws + o);    o += NTMAX * 4;
  int* slot_token = (int*)(ws + o); o += (size_t)NSLOT * 4;
  int* inv     = (int*)(ws + o);    o += (size_t)NSLOT * 4;
  float* slot_w = (float*)(ws + o); o += (size_t)NSLOT * 4;
  o = (o + 255) & ~(size_t)255;
  u16* act = (u16*)(ws + o);        o += (size_t)NSLOT * IW * 2;         // 16 MiB
  u16* wdown = (u16*)(ws + o);      o += (size_t)NSLOT * HH * 2;         // 16 MiB
  // total ~130.5 MiB of ws

  k_route<<<1, 256, 0, stream>>>(idx, tkw, offsets, slot_token, slot_w, inv,
                                 tile_e, tile_mt);
  k_cvt_all<<<25088, 256, 0, stream>>>(hs, gup, dpw, xb, gupb, dpb);
  k_gemm1<<<dim3(IW / 64, NTMAX), 256, 0, stream>>>(xb, gupb, offsets, slot_token,
                                                    slot_w, tile_e, tile_mt, act);
  k_gemm2<<<dim3(HH / 128, NTMAX), 256, 0, stream>>>(act, dpb, offsets, tile_e,
                                                     tile_mt, wdown);
  k_combine<<<TT * HH / 8 / 256, 256, 0, stream>>>(wdown, inv, out);
}